// Round 16
// baseline (1352.347 us; speedup 1.0000x reference)
//
#include <hip/hip_runtime.h>
#include <math.h>

#define BN_EPS 1e-5f
#define RS 68  // row stride (words): 16B-aligned rows, b128-conflict-minimal

typedef float v2f __attribute__((ext_vector_type(2)));

// Exact-path transposed weights [ci][t][co]. g_wgT is UNSCALED (bit-exact
// gating fallback). Expert conv2/3 weights carry the BN scale folded in.
__device__ __align__(16) float g_wgT[24576 + 192];  // gating conv1 (fallback)
__device__ __align__(16) float g_we2T[18432 + 96];  // expert conv2 (xBN scale)
__device__ __align__(16) float g_we3T[4608 + 48];   // expert conv3 (xBN scale)

// fp32 token-indexed conv1 tables with BN FOLDED IN (scale on all planes,
// bias on the t=1 plane). Layout [t][v][64ch], v=64 row = zeros (pad edges).
__device__ __align__(16) float g_Pf[12480];   // gating  [3][65][64]
__device__ __align__(16) float e_Pf[37440];   // experts [3][3][65][64]
__device__ float c2_add[96], c3_add[48];

__global__ __launch_bounds__(256) void transpose_w_kernel(
    const float* __restrict__ gw, const float* __restrict__ e2w,
    const float* __restrict__ e3w, const float* __restrict__ ebn2,
    const float* __restrict__ ebn3) {
  int idx = blockIdx.x * 256 + threadIdx.x;
  if (idx < 24576) {
    int co = idx & 63, r = idx >> 6;
    int t = r % 3, ci = r / 3;
    g_wgT[idx] = gw[(co * 128 + ci) * 3 + t];
  } else if (idx < 24576 + 18432) {
    int jj = idx - 24576;
    int e = jj / 6144, j = jj % 6144;
    int co = j & 31, r = j >> 5;
    int t = r % 3, ci = r / 3;
    const float* bn = ebn2 + e * 128;
    float inv = bn[co] / sqrtf(bn[96 + co] + BN_EPS);
    g_we2T[jj] = e2w[e * 6144 + (co * 64 + ci) * 3 + t] * inv;
  } else if (idx < 24576 + 18432 + 4608) {
    int jj = idx - (24576 + 18432);
    int e = jj / 1536, j = jj % 1536;
    int co = j & 15, r = j >> 4;
    int t = r % 3, ci = r / 3;
    const float* bn = ebn3 + e * 64;
    float inv = bn[co] / sqrtf(bn[48 + co] + BN_EPS);
    g_we3T[jj] = e3w[e * 1536 + (co * 32 + ci) * 3 + t] * inv;
  }
}

__global__ __launch_bounds__(256) void build_p_kernel(
    const float* __restrict__ embt, const float* __restrict__ gw,
    const float* __restrict__ e1w, const float* __restrict__ gbn,
    const float* __restrict__ gcb, const float* __restrict__ ebn1,
    const float* __restrict__ e1b, const float* __restrict__ ebn2,
    const float* __restrict__ e2b, const float* __restrict__ ebn3,
    const float* __restrict__ e3b) {
  int idx = blockIdx.x * 256 + threadIdx.x;
  if (idx < 12480) {
    int co = idx & 63, r = idx >> 6;
    int v = r % 65, t = r / 65;
    float a = 0.f;
    if (v < 64) {
      float dot = 0.f;
#pragma unroll 8
      for (int ci = 0; ci < 128; ++ci)
        dot = fmaf(embt[v * 128 + ci], gw[(co * 128 + ci) * 3 + t], dot);
      float inv = gbn[co] / sqrtf(gbn[192 + co] + BN_EPS);
      float add = gbn[64 + co] + (gcb[co] - gbn[128 + co]) * inv;
      a = (t == 1) ? fmaf(dot, inv, add) : dot * inv;
    }
    g_Pf[idx] = a;
  } else if (idx < 12480 + 37440) {
    int j = idx - 12480;
    int co = j & 63, r = j >> 6;
    int v = r % 65, tt = r / 65;
    int t = tt % 3, e = tt / 3;
    float a = 0.f;
    if (v < 64) {
      float dot = 0.f;
#pragma unroll 8
      for (int ci = 0; ci < 128; ++ci)
        dot = fmaf(embt[v * 128 + ci],
                   e1w[e * 24576 + (co * 128 + ci) * 3 + t], dot);
      const float* bn = ebn1 + e * 256;
      float inv = bn[co] / sqrtf(bn[192 + co] + BN_EPS);
      float add = bn[64 + co] + (e1b[e * 64 + co] - bn[128 + co]) * inv;
      a = (t == 1) ? fmaf(dot, inv, add) : dot * inv;
    }
    e_Pf[j] = a;
  } else if (idx < 12480 + 37440 + 144) {
    int q = idx - (12480 + 37440);
    if (q < 96) {
      int e = q >> 5, co = q & 31;
      const float* bn = ebn2 + e * 128;
      float inv = bn[co] / sqrtf(bn[96 + co] + BN_EPS);
      c2_add[q] = bn[32 + co] + (e2b[e * 32 + co] - bn[64 + co]) * inv;
    } else {
      int j = q - 96;
      int e = j >> 4, co = j & 15;
      const float* bn = ebn3 + e * 64;
      float inv = bn[co] / sqrtf(bn[48 + co] + BN_EPS);
      c3_add[j] = bn[16 + co] + (e3b[e * 16 + co] - bn[32 + co]) * inv;
    }
  }
}

// ---- exact conv (bit-matches np, fallback only): 3 LDS reads/ci ----
template <int CIN, int CO, int NCO>
__device__ __forceinline__ void convG(const float* __restrict__ wT,
                                      const float* E, int l,
                                      v2f (&acc)[NCO / 2]) {
#pragma unroll 4
  for (int ci = 0; ci < CIN; ++ci) {
    const float* row = E + ci * 64 + l;
    float e0 = row[0], e1 = row[1], e2 = row[2];
    v2f e0v = {e0, e0}, e1v = {e1, e1}, e2v = {e2, e2};
    const float* wrow = wT + ci * (3 * CO);
#pragma unroll
    for (int k2 = 0; k2 < NCO / 2; ++k2) {
      v2f w0 = *reinterpret_cast<const v2f*>(wrow + 2 * k2);
      v2f w1 = *reinterpret_cast<const v2f*>(wrow + CO + 2 * k2);
      v2f w2 = *reinterpret_cast<const v2f*>(wrow + 2 * CO + 2 * k2);
      acc[k2] = __builtin_elementwise_fma(
          e0v, w0,
          __builtin_elementwise_fma(
              e1v, w1, __builtin_elementwise_fma(e2v, w2, acc[k2])));
    }
  }
}

// ---- scatter conv, position-major input: lane reads ONLY its own row
// (position lane). ds_read_b128: 4 ci per read. Lane l's input feeds
// out[l+1] via w0 (A0), out[l] via w1 (A1), out[l-1] via w2 (A2):
//   out@lane = A0@(lane-1) + A1@lane + A2@(lane+1)
template <int CIN, int CO, int NCO>
__device__ __forceinline__ void convAT(const float* __restrict__ wT,
                                       const float* Erow,
                                       v2f (&A0)[NCO / 2], v2f (&A1)[NCO / 2],
                                       v2f (&A2)[NCO / 2]) {
  const float4* ep = reinterpret_cast<const float4*>(Erow);
#pragma unroll 2
  for (int c4 = 0; c4 < CIN / 4; ++c4) {
    float4 ev = ep[c4];
    const float ee[4] = {ev.x, ev.y, ev.z, ev.w};
#pragma unroll
    for (int j = 0; j < 4; ++j) {
      const int ci = 4 * c4 + j;
      v2f rv = {ee[j], ee[j]};
      const float* wrow = wT + ci * (3 * CO);
#pragma unroll
      for (int k2 = 0; k2 < NCO / 2; ++k2) {
        v2f w0 = *reinterpret_cast<const v2f*>(wrow + 2 * k2);
        v2f w1 = *reinterpret_cast<const v2f*>(wrow + CO + 2 * k2);
        v2f w2 = *reinterpret_cast<const v2f*>(wrow + 2 * CO + 2 * k2);
        A0[k2] = __builtin_elementwise_fma(rv, w0, A0[k2]);
        A1[k2] = __builtin_elementwise_fma(rv, w1, A1[k2]);
        A2[k2] = __builtin_elementwise_fma(rv, w2, A2[k2]);
      }
    }
  }
}

__global__ __launch_bounds__(256, 8) void moe_fused_kernel(
    const int* __restrict__ x, const float* __restrict__ embt,
    const float* __restrict__ gcb, const float* __restrict__ gbn,
    const float* __restrict__ gf1w, const float* __restrict__ gf1b,
    const float* __restrict__ gf2w, const float* __restrict__ gf2b,
    const float* __restrict__ f1w, const float* __restrict__ f1b,
    const float* __restrict__ f2w, const float* __restrict__ f2b,
    float* __restrict__ out) {
  // smem: Abuf[64 pos][RS=68] (gating Gbuf, then expert activations;
  //       conv3 out in cols 48..63; fallback aliases words [0,4028))
  //       + Pbuf 256 + hbuf 64 + h2buf 32 + glog 4 + mbuf 16 + o64
  __shared__ __align__(16) float smem[4800];
  float* Abuf = smem;  // rows 60..63 zeroed once, never written again
  float* Pbuf = smem + 4352;
  float* hbuf = smem + 4608;
  float* h2buf = smem + 4672;
  float* glog = smem + 4704;
  float* mbuf = smem + 4708;
  float* o64 = smem + 4724;
  __shared__ int toks[64];
  __shared__ int selbuf, fbflag;

  const int b = blockIdx.x;
  const int tid = threadIdx.x;
  const int lane = tid & 63;
  const int wv = tid >> 6;
  const int wvu = __builtin_amdgcn_readfirstlane(wv);
  const bool valid = (lane < 60);
  const int cob = wvu * 16;

  if (tid < 64) toks[tid] = x[b * 60 + (tid < 60 ? tid : 59)];
  // zero rows 60..63 once (words 4080..4351); all later stores lane-guarded
  for (int i = tid; i < 272; i += 256) Abuf[4080 + i] = 0.f;
  __syncthreads();

  // s[k] = conv1 post-BN pre-relu value for co=cob+k at position lane
  auto table_sum = [&](const float* __restrict__ P, float(&s)[16]) {
    const int l = lane;
    const int v0 = l ? toks[l - 1] : 64;
    const int v1 = toks[l];
    const int v2 = (l < 59) ? toks[l + 1] : 64;
    const float4* r0 = reinterpret_cast<const float4*>(P + v0 * 64 + cob);
    const float4* r1 =
        reinterpret_cast<const float4*>(P + 4160 + v1 * 64 + cob);
    const float4* r2 =
        reinterpret_cast<const float4*>(P + 8320 + v2 * 64 + cob);
#pragma unroll
    for (int q = 0; q < 4; ++q) {
      float4 a0 = r0[q], a1 = r1[q], a2 = r2[q];
      s[4 * q + 0] = (a1.x + a0.x) + a2.x;
      s[4 * q + 1] = (a1.y + a0.y) + a2.y;
      s[4 * q + 2] = (a1.z + a0.z) + a2.z;
      s[4 * q + 3] = (a1.w + a0.w) + a2.w;
    }
  };

  // ---- gating conv1 (table): RAW values -> Abuf row lane (b128 stores).
  // relu deferred to after the max (exact: max(relu x) == max(max x, 0)).
  {
    float s[16];
    table_sum(g_Pf, s);
    if (valid) {
      float4* dst = reinterpret_cast<float4*>(Abuf + lane * RS + cob);
#pragma unroll
      for (int q = 0; q < 4; ++q)
        dst[q] = make_float4(s[4 * q], s[4 * q + 1], s[4 * q + 2],
                             s[4 * q + 3]);
    }
  }
  __syncthreads();
  // max over rows 0..59: 256 threads, (channel, 15-row strip) each
  {
    const int ch = tid & 63, q = tid >> 6;
    const float* col = Abuf + (q * 15) * RS + ch;
    float m = col[0];
#pragma unroll
    for (int i = 1; i < 15; ++i) m = fmaxf(m, col[i * RS]);
    Pbuf[q * 64 + ch] = m;
  }
  __syncthreads();
  if (tid < 64)
    hbuf[tid] = fmaxf(fmaxf(fmaxf(Pbuf[tid], Pbuf[64 + tid]),
                            fmaxf(Pbuf[128 + tid], Pbuf[192 + tid])),
                      0.f);
  __syncthreads();

  // ---- gating MLP 64->32 (parallel tree) ----
  {
    const int o = tid >> 3, p = tid & 7;
    const float* wrow = gf1w + o * 64 + p * 8;
    float4 wa = reinterpret_cast<const float4*>(wrow)[0];
    float4 wb = reinterpret_cast<const float4*>(wrow)[1];
    const float* hh = hbuf + p * 8;
    float a = 0.f;
    a = fmaf(hh[0], wa.x, a);
    a = fmaf(hh[1], wa.y, a);
    a = fmaf(hh[2], wa.z, a);
    a = fmaf(hh[3], wa.w, a);
    a = fmaf(hh[4], wb.x, a);
    a = fmaf(hh[5], wb.y, a);
    a = fmaf(hh[6], wb.z, a);
    a = fmaf(hh[7], wb.w, a);
    a += __shfl_xor(a, 1, 64);
    a += __shfl_xor(a, 2, 64);
    a += __shfl_xor(a, 4, 64);
    if (p == 0) h2buf[o] = fmaxf(a + gf1b[o], 0.f);
  }
  __syncthreads();
  if (tid < 96) {
    const int o = tid >> 5, j = tid & 31;
    float a = h2buf[j] * gf2w[o * 32 + j];
    a += __shfl_xor(a, 1, 32);
    a += __shfl_xor(a, 2, 32);
    a += __shfl_xor(a, 4, 32);
    a += __shfl_xor(a, 8, 32);
    a += __shfl_xor(a, 16, 32);
    if (j == 0) glog[o] = a + gf2b[o];
  }
  __syncthreads();
  if (tid == 0) {
    int best = 0;
    float bv = glog[0];
    if (glog[1] > bv) { bv = glog[1]; best = 1; }
    if (glog[2] > bv) { bv = glog[2]; best = 2; }
    float second = -1e30f;
#pragma unroll
    for (int i = 0; i < 3; ++i)
      if (i != best) second = fmaxf(second, glog[i]);
    selbuf = best;
    fbflag = (bv - second < 2e-4f) ? 1 : 0;
  }
  __syncthreads();

  if (fbflag) {
    // rare near-tie: recompute gating bit-exactly and re-derive argmax.
    float* tileF = smem;          // words [0,2048)
    float* TbufF = smem + 2048;   // words [2048,4028) — below row-60 zeros
    if (tid < 128) {
      int r = tid >> 2;
      const int ctab[4] = {0, 61, 62, 63};
      tileF[r * 64 + ctab[tid & 3]] = 0.f;
    }
    v2f acc[8] = {};
    for (int tile = 0; tile < 4; ++tile) {
      for (int i = tid; i < 60 * 32; i += 256) {
        int l = i >> 5, dp = i & 31;
        TbufF[l * 33 + dp] = embt[toks[l] * 128 + tile * 32 + dp];
      }
      __syncthreads();
      if (valid) {
#pragma unroll
        for (int dp = wvu; dp < 32; dp += 4)
          tileF[dp * 64 + lane + 1] = TbufF[lane * 33 + dp];
      }
      __syncthreads();
      convG<32, 64, 16>(g_wgT + tile * 32 * 192 + cob, tileF, lane, acc);
      __syncthreads();
    }
#pragma unroll
    for (int k = 0; k < 16; ++k) {
      int co = cob + k;
      float inv = gbn[co] / sqrtf(gbn[192 + co] + BN_EPS);
      float add = gbn[64 + co] + (gcb[co] - gbn[128 + co]) * inv;
      float v = valid ? fmaxf(fmaf(acc[k >> 1][k & 1], inv, add), 0.f) : 0.f;
#pragma unroll
      for (int off = 1; off < 64; off <<= 1)
        v = fmaxf(v, __shfl_xor(v, off, 64));
      if (lane == 0) hbuf[co] = v;
    }
    __syncthreads();
    if (tid < 32) {
      float a = gf1b[tid];
#pragma unroll 8
      for (int k = 0; k < 64; ++k) a = fmaf(hbuf[k], gf1w[tid * 64 + k], a);
      h2buf[tid] = fmaxf(a, 0.f);
    }
    __syncthreads();
    if (tid < 3) {
      float a = gf2b[tid];
#pragma unroll 8
      for (int k = 0; k < 32; ++k) a = fmaf(h2buf[k], gf2w[tid * 32 + k], a);
      glog[tid] = a;
    }
    __syncthreads();
    if (tid == 0) {
      int best = 0;
      float bv = glog[0];
      if (glog[1] > bv) { bv = glog[1]; best = 1; }
      if (glog[2] > bv) { best = 2; }
      selbuf = best;
    }
    __syncthreads();
  }
  const int e = __builtin_amdgcn_readfirstlane(selbuf);

  // ---- expert conv1 (table) + ReLU -> Abuf row lane (b128 stores) ----
  {
    float s[16];
    table_sum(e_Pf + e * 12480, s);
    if (valid) {
      float4* dst = reinterpret_cast<float4*>(Abuf + lane * RS + cob);
#pragma unroll
      for (int q = 0; q < 4; ++q)
        dst[q] = make_float4(fmaxf(s[4 * q], 0.f), fmaxf(s[4 * q + 1], 0.f),
                             fmaxf(s[4 * q + 2], 0.f),
                             fmaxf(s[4 * q + 3], 0.f));
    }
  }
  __syncthreads();

  // ---- expert conv2 (scatter, own-row b128 reads): cols 0..63 -> 0..31 ----
  {
    v2f A0[4] = {}, A1[4] = {}, A2[4] = {};
    const int cob2 = wvu * 8;
    convAT<64, 32, 8>(g_we2T + e * 6144 + cob2, Abuf + lane * RS, A0, A1, A2);
    float val8[8];
#pragma unroll
    for (int k = 0; k < 8; ++k) {
      int co = cob2 + k;
      float a0 = __shfl(A0[k >> 1][k & 1], (lane + 63) & 63, 64);  // lane-1
      float a2 = __shfl(A2[k >> 1][k & 1], lane + 1, 64);
      float ss = (a0 + A1[k >> 1][k & 1]) + a2;
      val8[k] = fmaxf(ss + c2_add[e * 32 + co], 0.f);
    }
    __syncthreads();  // all row reads done before overwrite
    if (valid) {
      float4* dst = reinterpret_cast<float4*>(Abuf + lane * RS + cob2);
      dst[0] = make_float4(val8[0], val8[1], val8[2], val8[3]);
      dst[1] = make_float4(val8[4], val8[5], val8[6], val8[7]);
    }
  }
  __syncthreads();

  // ---- expert conv3 (scatter): cols 0..31 -> RAW to cols 48..63 ----
  {
    v2f A0[2] = {}, A1[2] = {}, A2[2] = {};
    const int cob3 = wvu * 4;
    convAT<32, 16, 4>(g_we3T + e * 1536 + cob3, Abuf + lane * RS, A0, A1, A2);
    float v4[4];
#pragma unroll
    for (int k = 0; k < 4; ++k) {
      int co = cob3 + k;
      float a0 = __shfl(A0[k >> 1][k & 1], (lane + 63) & 63, 64);  // lane-1
      float a2 = __shfl(A2[k >> 1][k & 1], lane + 1, 64);
      v4[k] = ((a0 + A1[k >> 1][k & 1]) + a2) + c3_add[e * 16 + co];
    }
    // write cols 48..63: disjoint from the cols 0..31 others still read
    if (valid)
      *reinterpret_cast<float4*>(Abuf + lane * RS + 48 + cob3) =
          make_float4(v4[0], v4[1], v4[2], v4[3]);
  }
  __syncthreads();
  // max over rows 0..59 (relu deferred): 64 threads, 15-row strips
  if (tid < 64) {
    const int ch = tid & 15, q = tid >> 4;
    const float* col = Abuf + (q * 15) * RS + 48 + ch;
    float m = col[0];
#pragma unroll
    for (int i = 1; i < 15; ++i) m = fmaxf(m, col[i * RS]);
    Pbuf[q * 16 + ch] = m;
  }
  __syncthreads();
  if (tid < 16)
    mbuf[tid] = fmaxf(fmaxf(fmaxf(Pbuf[tid], Pbuf[16 + tid]),
                            fmaxf(Pbuf[32 + tid], Pbuf[48 + tid])),
                      0.f);
  __syncthreads();

  // ---- head MLP 16->64->2 ----
  if (tid < 64) {
    float a = f1b[tid];
#pragma unroll
    for (int k = 0; k < 16; ++k) a = fmaf(mbuf[k], f1w[tid * 16 + k], a);
    o64[tid] = fmaxf(a, 0.f);
  }
  __syncthreads();
  if (tid < 128) {
    const int o = tid >> 6, j = tid & 63;
    float a = o64[j] * f2w[o * 64 + j];
    a += __shfl_xor(a, 1, 64);
    a += __shfl_xor(a, 2, 64);
    a += __shfl_xor(a, 4, 64);
    a += __shfl_xor(a, 8, 64);
    a += __shfl_xor(a, 16, 64);
    a += __shfl_xor(a, 32, 64);
    if (j == 0) out[b * 2 + o] = a + f2b[o];
  }
}

extern "C" void kernel_launch(void* const* d_in, const int* in_sizes, int n_in,
                              void* d_out, int out_size, void* d_ws,
                              size_t ws_size, hipStream_t stream) {
  const int* x = (const int*)d_in[0];
  const float* embt = (const float*)d_in[1];
  const float* gcw = (const float*)d_in[2];
  const float* gcb = (const float*)d_in[3];
  const float* gbn = (const float*)d_in[4];
  const float* gf1w = (const float*)d_in[5];
  const float* gf1b = (const float*)d_in[6];
  const float* gf2w = (const float*)d_in[7];
  const float* gf2b = (const float*)d_in[8];
  const float* e1w = (const float*)d_in[9];
  const float* e1b = (const float*)d_in[10];
  const float* ebn1 = (const float*)d_in[11];
  const float* e2w = (const float*)d_in[12];
  const float* e2b = (const float*)d_in[13];
  const float* ebn2 = (const float*)d_in[14];
  const float* e3w = (const float*)d_in[15];
  const float* e3b = (const float*)d_in[16];
  const float* ebn3 = (const float*)d_in[17];
  const float* f1w = (const float*)d_in[18];
  const float* f1b = (const float*)d_in[19];
  const float* f2w = (const float*)d_in[20];
  const float* f2b = (const float*)d_in[21];
  float* out = (float*)d_out;

  const int B = in_sizes[0] / 60;  // 16384

  transpose_w_kernel<<<(47616 + 255) / 256, 256, 0, stream>>>(gcw, e2w, e3w,
                                                              ebn2, ebn3);
  build_p_kernel<<<(50064 + 255) / 256, 256, 0, stream>>>(
      embt, gcw, e1w, gbn, gcb, ebn1, e1b, ebn2, e2b, ebn3, e3b);
  moe_fused_kernel<<<B, 256, 0, stream>>>(x, embt, gcb, gbn, gf1w, gf1b, gf2w,
                                          gf2b, f1w, f1b, f2w, f2b, out);
}

// Round 17
// 1298.077 us; speedup vs baseline: 1.0418x; 1.0418x over previous
//
#include <hip/hip_runtime.h>
#include <math.h>

#define BN_EPS 1e-5f
#define RS 68  // row stride (words): 16B-aligned rows, b128-conflict-minimal

typedef float v2f __attribute__((ext_vector_type(2)));

// Exact-path transposed weights [ci][t][co]. g_wgT is UNSCALED (bit-exact
// gating fallback). Expert conv2/3 weights carry the BN scale folded in.
__device__ __align__(16) float g_wgT[24576 + 192];  // gating conv1 (fallback)
__device__ __align__(16) float g_we2T[18432 + 96];  // expert conv2 (xBN scale)
__device__ __align__(16) float g_we3T[4608 + 48];   // expert conv3 (xBN scale)

// fp32 token-indexed conv1 tables with BN FOLDED IN (scale on all planes,
// bias on the t=1 plane). Layout [t][v][64ch], v=64 row = zeros (pad edges).
__device__ __align__(16) float g_Pf[12480];   // gating  [3][65][64]
__device__ __align__(16) float e_Pf[37440];   // experts [3][3][65][64]
__device__ float c2_add[96], c3_add[48];

__global__ __launch_bounds__(256) void transpose_w_kernel(
    const float* __restrict__ gw, const float* __restrict__ e2w,
    const float* __restrict__ e3w, const float* __restrict__ ebn2,
    const float* __restrict__ ebn3) {
  int idx = blockIdx.x * 256 + threadIdx.x;
  if (idx < 24576) {
    int co = idx & 63, r = idx >> 6;
    int t = r % 3, ci = r / 3;
    g_wgT[idx] = gw[(co * 128 + ci) * 3 + t];
  } else if (idx < 24576 + 18432) {
    int jj = idx - 24576;
    int e = jj / 6144, j = jj % 6144;
    int co = j & 31, r = j >> 5;
    int t = r % 3, ci = r / 3;
    const float* bn = ebn2 + e * 128;
    float inv = bn[co] / sqrtf(bn[96 + co] + BN_EPS);
    g_we2T[jj] = e2w[e * 6144 + (co * 64 + ci) * 3 + t] * inv;
  } else if (idx < 24576 + 18432 + 4608) {
    int jj = idx - (24576 + 18432);
    int e = jj / 1536, j = jj % 1536;
    int co = j & 15, r = j >> 4;
    int t = r % 3, ci = r / 3;
    const float* bn = ebn3 + e * 64;
    float inv = bn[co] / sqrtf(bn[48 + co] + BN_EPS);
    g_we3T[jj] = e3w[e * 1536 + (co * 32 + ci) * 3 + t] * inv;
  }
}

__global__ __launch_bounds__(256) void build_p_kernel(
    const float* __restrict__ embt, const float* __restrict__ gw,
    const float* __restrict__ e1w, const float* __restrict__ gbn,
    const float* __restrict__ gcb, const float* __restrict__ ebn1,
    const float* __restrict__ e1b, const float* __restrict__ ebn2,
    const float* __restrict__ e2b, const float* __restrict__ ebn3,
    const float* __restrict__ e3b) {
  int idx = blockIdx.x * 256 + threadIdx.x;
  if (idx < 12480) {
    int co = idx & 63, r = idx >> 6;
    int v = r % 65, t = r / 65;
    float a = 0.f;
    if (v < 64) {
      float dot = 0.f;
#pragma unroll 8
      for (int ci = 0; ci < 128; ++ci)
        dot = fmaf(embt[v * 128 + ci], gw[(co * 128 + ci) * 3 + t], dot);
      float inv = gbn[co] / sqrtf(gbn[192 + co] + BN_EPS);
      float add = gbn[64 + co] + (gcb[co] - gbn[128 + co]) * inv;
      a = (t == 1) ? fmaf(dot, inv, add) : dot * inv;
    }
    g_Pf[idx] = a;
  } else if (idx < 12480 + 37440) {
    int j = idx - 12480;
    int co = j & 63, r = j >> 6;
    int v = r % 65, tt = r / 65;
    int t = tt % 3, e = tt / 3;
    float a = 0.f;
    if (v < 64) {
      float dot = 0.f;
#pragma unroll 8
      for (int ci = 0; ci < 128; ++ci)
        dot = fmaf(embt[v * 128 + ci],
                   e1w[e * 24576 + (co * 128 + ci) * 3 + t], dot);
      const float* bn = ebn1 + e * 256;
      float inv = bn[co] / sqrtf(bn[192 + co] + BN_EPS);
      float add = bn[64 + co] + (e1b[e * 64 + co] - bn[128 + co]) * inv;
      a = (t == 1) ? fmaf(dot, inv, add) : dot * inv;
    }
    e_Pf[j] = a;
  } else if (idx < 12480 + 37440 + 144) {
    int q = idx - (12480 + 37440);
    if (q < 96) {
      int e = q >> 5, co = q & 31;
      const float* bn = ebn2 + e * 128;
      float inv = bn[co] / sqrtf(bn[96 + co] + BN_EPS);
      c2_add[q] = bn[32 + co] + (e2b[e * 32 + co] - bn[64 + co]) * inv;
    } else {
      int j = q - 96;
      int e = j >> 4, co = j & 15;
      const float* bn = ebn3 + e * 64;
      float inv = bn[co] / sqrtf(bn[48 + co] + BN_EPS);
      c3_add[j] = bn[16 + co] + (e3b[e * 16 + co] - bn[32 + co]) * inv;
    }
  }
}

// ---- exact conv (bit-matches np, fallback only): 3 LDS reads/ci ----
template <int CIN, int CO, int NCO>
__device__ __forceinline__ void convG(const float* __restrict__ wT,
                                      const float* E, int l,
                                      v2f (&acc)[NCO / 2]) {
#pragma unroll 4
  for (int ci = 0; ci < CIN; ++ci) {
    const float* row = E + ci * 64 + l;
    float e0 = row[0], e1 = row[1], e2 = row[2];
    v2f e0v = {e0, e0}, e1v = {e1, e1}, e2v = {e2, e2};
    const float* wrow = wT + ci * (3 * CO);
#pragma unroll
    for (int k2 = 0; k2 < NCO / 2; ++k2) {
      v2f w0 = *reinterpret_cast<const v2f*>(wrow + 2 * k2);
      v2f w1 = *reinterpret_cast<const v2f*>(wrow + CO + 2 * k2);
      v2f w2 = *reinterpret_cast<const v2f*>(wrow + 2 * CO + 2 * k2);
      acc[k2] = __builtin_elementwise_fma(
          e0v, w0,
          __builtin_elementwise_fma(
              e1v, w1, __builtin_elementwise_fma(e2v, w2, acc[k2])));
    }
  }
}

// ---- scatter conv, position-major input: lane reads ONLY its own row
// (position lane). ds_read_b128: 4 ci per read. Lane l's input feeds
// out[l+1] via w0 (A0), out[l] via w1 (A1), out[l-1] via w2 (A2):
//   out@lane = A0@(lane-1) + A1@lane + A2@(lane+1)
template <int CIN, int CO, int NCO>
__device__ __forceinline__ void convAT(const float* __restrict__ wT,
                                       const float* Erow,
                                       v2f (&A0)[NCO / 2], v2f (&A1)[NCO / 2],
                                       v2f (&A2)[NCO / 2]) {
  const float4* ep = reinterpret_cast<const float4*>(Erow);
#pragma unroll 2
  for (int c4 = 0; c4 < CIN / 4; ++c4) {
    float4 ev = ep[c4];
    const float ee[4] = {ev.x, ev.y, ev.z, ev.w};
#pragma unroll
    for (int j = 0; j < 4; ++j) {
      const int ci = 4 * c4 + j;
      v2f rv = {ee[j], ee[j]};
      const float* wrow = wT + ci * (3 * CO);
#pragma unroll
      for (int k2 = 0; k2 < NCO / 2; ++k2) {
        v2f w0 = *reinterpret_cast<const v2f*>(wrow + 2 * k2);
        v2f w1 = *reinterpret_cast<const v2f*>(wrow + CO + 2 * k2);
        v2f w2 = *reinterpret_cast<const v2f*>(wrow + 2 * CO + 2 * k2);
        A0[k2] = __builtin_elementwise_fma(rv, w0, A0[k2]);
        A1[k2] = __builtin_elementwise_fma(rv, w1, A1[k2]);
        A2[k2] = __builtin_elementwise_fma(rv, w2, A2[k2]);
      }
    }
  }
}

// launch_bounds (256,6): VGPR cap ~85 so convAT's live set (~48) fits
// WITHOUT scratch spill (the (256,8)=32-VGPR cap caused 200 MB/dispatch of
// spill traffic in R16). Occupancy stays LDS-capped at 8 blocks/CU as long
// as actual allocation <= 64.
__global__ __launch_bounds__(256, 6) void moe_fused_kernel(
    const int* __restrict__ x, const float* __restrict__ embt,
    const float* __restrict__ gcb, const float* __restrict__ gbn,
    const float* __restrict__ gf1w, const float* __restrict__ gf1b,
    const float* __restrict__ gf2w, const float* __restrict__ gf2b,
    const float* __restrict__ f1w, const float* __restrict__ f1b,
    const float* __restrict__ f2w, const float* __restrict__ f2b,
    float* __restrict__ out) {
  // smem: Abuf[64 pos][RS=68] (gating Gbuf, then expert activations;
  //       conv3 out in cols 48..63; fallback aliases words [0,4028))
  //       + Pbuf 256 + hbuf 64 + h2buf 32 + glog 4 + mbuf 16 + o64
  __shared__ __align__(16) float smem[4800];
  float* Abuf = smem;  // rows 60..63 zeroed once, never written again
  float* Pbuf = smem + 4352;
  float* hbuf = smem + 4608;
  float* h2buf = smem + 4672;
  float* glog = smem + 4704;
  float* mbuf = smem + 4708;
  float* o64 = smem + 4724;
  __shared__ int toks[64];
  __shared__ int selbuf, fbflag;

  const int b = blockIdx.x;
  const int tid = threadIdx.x;
  const int lane = tid & 63;
  const int wv = tid >> 6;
  const int wvu = __builtin_amdgcn_readfirstlane(wv);
  const bool valid = (lane < 60);
  const int cob = wvu * 16;

  if (tid < 64) toks[tid] = x[b * 60 + (tid < 60 ? tid : 59)];
  // zero rows 60..63 once (words 4080..4351); all later stores lane-guarded
  for (int i = tid; i < 272; i += 256) Abuf[4080 + i] = 0.f;
  __syncthreads();

  // s[k] = conv1 post-BN pre-relu value for co=cob+k at position lane
  auto table_sum = [&](const float* __restrict__ P, float(&s)[16]) {
    const int l = lane;
    const int v0 = l ? toks[l - 1] : 64;
    const int v1 = toks[l];
    const int v2 = (l < 59) ? toks[l + 1] : 64;
    const float4* r0 = reinterpret_cast<const float4*>(P + v0 * 64 + cob);
    const float4* r1 =
        reinterpret_cast<const float4*>(P + 4160 + v1 * 64 + cob);
    const float4* r2 =
        reinterpret_cast<const float4*>(P + 8320 + v2 * 64 + cob);
#pragma unroll
    for (int q = 0; q < 4; ++q) {
      float4 a0 = r0[q], a1 = r1[q], a2 = r2[q];
      s[4 * q + 0] = (a1.x + a0.x) + a2.x;
      s[4 * q + 1] = (a1.y + a0.y) + a2.y;
      s[4 * q + 2] = (a1.z + a0.z) + a2.z;
      s[4 * q + 3] = (a1.w + a0.w) + a2.w;
    }
  };

  // ---- gating conv1 (table): RAW values -> Abuf row lane (b128 stores).
  // relu deferred to after the max (exact: max(relu x) == max(max x, 0)).
  {
    float s[16];
    table_sum(g_Pf, s);
    if (valid) {
      float4* dst = reinterpret_cast<float4*>(Abuf + lane * RS + cob);
#pragma unroll
      for (int q = 0; q < 4; ++q)
        dst[q] = make_float4(s[4 * q], s[4 * q + 1], s[4 * q + 2],
                             s[4 * q + 3]);
    }
  }
  __syncthreads();
  // max over rows 0..59: 256 threads, (channel, 15-row strip) each
  {
    const int ch = tid & 63, q = tid >> 6;
    const float* col = Abuf + (q * 15) * RS + ch;
    float m = col[0];
#pragma unroll
    for (int i = 1; i < 15; ++i) m = fmaxf(m, col[i * RS]);
    Pbuf[q * 64 + ch] = m;
  }
  __syncthreads();
  if (tid < 64)
    hbuf[tid] = fmaxf(fmaxf(fmaxf(Pbuf[tid], Pbuf[64 + tid]),
                            fmaxf(Pbuf[128 + tid], Pbuf[192 + tid])),
                      0.f);
  __syncthreads();

  // ---- gating MLP 64->32 (parallel tree) ----
  {
    const int o = tid >> 3, p = tid & 7;
    const float* wrow = gf1w + o * 64 + p * 8;
    float4 wa = reinterpret_cast<const float4*>(wrow)[0];
    float4 wb = reinterpret_cast<const float4*>(wrow)[1];
    const float* hh = hbuf + p * 8;
    float a = 0.f;
    a = fmaf(hh[0], wa.x, a);
    a = fmaf(hh[1], wa.y, a);
    a = fmaf(hh[2], wa.z, a);
    a = fmaf(hh[3], wa.w, a);
    a = fmaf(hh[4], wb.x, a);
    a = fmaf(hh[5], wb.y, a);
    a = fmaf(hh[6], wb.z, a);
    a = fmaf(hh[7], wb.w, a);
    a += __shfl_xor(a, 1, 64);
    a += __shfl_xor(a, 2, 64);
    a += __shfl_xor(a, 4, 64);
    if (p == 0) h2buf[o] = fmaxf(a + gf1b[o], 0.f);
  }
  __syncthreads();
  if (tid < 96) {
    const int o = tid >> 5, j = tid & 31;
    float a = h2buf[j] * gf2w[o * 32 + j];
    a += __shfl_xor(a, 1, 32);
    a += __shfl_xor(a, 2, 32);
    a += __shfl_xor(a, 4, 32);
    a += __shfl_xor(a, 8, 32);
    a += __shfl_xor(a, 16, 32);
    if (j == 0) glog[o] = a + gf2b[o];
  }
  __syncthreads();
  if (tid == 0) {
    int best = 0;
    float bv = glog[0];
    if (glog[1] > bv) { bv = glog[1]; best = 1; }
    if (glog[2] > bv) { bv = glog[2]; best = 2; }
    float second = -1e30f;
#pragma unroll
    for (int i = 0; i < 3; ++i)
      if (i != best) second = fmaxf(second, glog[i]);
    selbuf = best;
    fbflag = (bv - second < 2e-4f) ? 1 : 0;
  }
  __syncthreads();

  if (fbflag) {
    // rare near-tie: recompute gating bit-exactly and re-derive argmax.
    float* tileF = smem;          // words [0,2048)
    float* TbufF = smem + 2048;   // words [2048,4028) — below row-60 zeros
    if (tid < 128) {
      int r = tid >> 2;
      const int ctab[4] = {0, 61, 62, 63};
      tileF[r * 64 + ctab[tid & 3]] = 0.f;
    }
    v2f acc[8] = {};
    for (int tile = 0; tile < 4; ++tile) {
      for (int i = tid; i < 60 * 32; i += 256) {
        int l = i >> 5, dp = i & 31;
        TbufF[l * 33 + dp] = embt[toks[l] * 128 + tile * 32 + dp];
      }
      __syncthreads();
      if (valid) {
#pragma unroll
        for (int dp = wvu; dp < 32; dp += 4)
          tileF[dp * 64 + lane + 1] = TbufF[lane * 33 + dp];
      }
      __syncthreads();
      convG<32, 64, 16>(g_wgT + tile * 32 * 192 + cob, tileF, lane, acc);
      __syncthreads();
    }
#pragma unroll
    for (int k = 0; k < 16; ++k) {
      int co = cob + k;
      float inv = gbn[co] / sqrtf(gbn[192 + co] + BN_EPS);
      float add = gbn[64 + co] + (gcb[co] - gbn[128 + co]) * inv;
      float v = valid ? fmaxf(fmaf(acc[k >> 1][k & 1], inv, add), 0.f) : 0.f;
#pragma unroll
      for (int off = 1; off < 64; off <<= 1)
        v = fmaxf(v, __shfl_xor(v, off, 64));
      if (lane == 0) hbuf[co] = v;
    }
    __syncthreads();
    if (tid < 32) {
      float a = gf1b[tid];
#pragma unroll 8
      for (int k = 0; k < 64; ++k) a = fmaf(hbuf[k], gf1w[tid * 64 + k], a);
      h2buf[tid] = fmaxf(a, 0.f);
    }
    __syncthreads();
    if (tid < 3) {
      float a = gf2b[tid];
#pragma unroll 8
      for (int k = 0; k < 32; ++k) a = fmaf(h2buf[k], gf2w[tid * 32 + k], a);
      glog[tid] = a;
    }
    __syncthreads();
    if (tid == 0) {
      int best = 0;
      float bv = glog[0];
      if (glog[1] > bv) { bv = glog[1]; best = 1; }
      if (glog[2] > bv) { best = 2; }
      selbuf = best;
    }
    __syncthreads();
  }
  const int e = __builtin_amdgcn_readfirstlane(selbuf);

  // ---- expert conv1 (table) + ReLU -> Abuf row lane (b128 stores) ----
  {
    float s[16];
    table_sum(e_Pf + e * 12480, s);
    if (valid) {
      float4* dst = reinterpret_cast<float4*>(Abuf + lane * RS + cob);
#pragma unroll
      for (int q = 0; q < 4; ++q)
        dst[q] = make_float4(fmaxf(s[4 * q], 0.f), fmaxf(s[4 * q + 1], 0.f),
                             fmaxf(s[4 * q + 2], 0.f),
                             fmaxf(s[4 * q + 3], 0.f));
    }
  }
  __syncthreads();

  // ---- expert conv2 (scatter, own-row b128 reads): cols 0..63 -> 0..31 ----
  {
    v2f A0[4] = {}, A1[4] = {}, A2[4] = {};
    const int cob2 = wvu * 8;
    convAT<64, 32, 8>(g_we2T + e * 6144 + cob2, Abuf + lane * RS, A0, A1, A2);
    float val8[8];
#pragma unroll
    for (int k = 0; k < 8; ++k) {
      int co = cob2 + k;
      float a0 = __shfl(A0[k >> 1][k & 1], (lane + 63) & 63, 64);  // lane-1
      float a2 = __shfl(A2[k >> 1][k & 1], lane + 1, 64);
      float ss = (a0 + A1[k >> 1][k & 1]) + a2;
      val8[k] = fmaxf(ss + c2_add[e * 32 + co], 0.f);
    }
    __syncthreads();  // all row reads done before overwrite
    if (valid) {
      float4* dst = reinterpret_cast<float4*>(Abuf + lane * RS + cob2);
      dst[0] = make_float4(val8[0], val8[1], val8[2], val8[3]);
      dst[1] = make_float4(val8[4], val8[5], val8[6], val8[7]);
    }
  }
  __syncthreads();

  // ---- expert conv3 (scatter): cols 0..31 -> RAW to cols 48..63 ----
  {
    v2f A0[2] = {}, A1[2] = {}, A2[2] = {};
    const int cob3 = wvu * 4;
    convAT<32, 16, 4>(g_we3T + e * 1536 + cob3, Abuf + lane * RS, A0, A1, A2);
    float v4[4];
#pragma unroll
    for (int k = 0; k < 4; ++k) {
      int co = cob3 + k;
      float a0 = __shfl(A0[k >> 1][k & 1], (lane + 63) & 63, 64);  // lane-1
      float a2 = __shfl(A2[k >> 1][k & 1], lane + 1, 64);
      v4[k] = ((a0 + A1[k >> 1][k & 1]) + a2) + c3_add[e * 16 + co];
    }
    // write cols 48..63: disjoint from the cols 0..31 others still read
    if (valid)
      *reinterpret_cast<float4*>(Abuf + lane * RS + 48 + cob3) =
          make_float4(v4[0], v4[1], v4[2], v4[3]);
  }
  __syncthreads();
  // max over rows 0..59 (relu deferred): 64 threads, 15-row strips
  if (tid < 64) {
    const int ch = tid & 15, q = tid >> 4;
    const float* col = Abuf + (q * 15) * RS + 48 + ch;
    float m = col[0];
#pragma unroll
    for (int i = 1; i < 15; ++i) m = fmaxf(m, col[i * RS]);
    Pbuf[q * 16 + ch] = m;
  }
  __syncthreads();
  if (tid < 16)
    mbuf[tid] = fmaxf(fmaxf(fmaxf(Pbuf[tid], Pbuf[16 + tid]),
                            fmaxf(Pbuf[32 + tid], Pbuf[48 + tid])),
                      0.f);
  __syncthreads();

  // ---- head MLP 16->64->2 ----
  if (tid < 64) {
    float a = f1b[tid];
#pragma unroll
    for (int k = 0; k < 16; ++k) a = fmaf(mbuf[k], f1w[tid * 16 + k], a);
    o64[tid] = fmaxf(a, 0.f);
  }
  __syncthreads();
  if (tid < 128) {
    const int o = tid >> 6, j = tid & 63;
    float a = o64[j] * f2w[o * 64 + j];
    a += __shfl_xor(a, 1, 64);
    a += __shfl_xor(a, 2, 64);
    a += __shfl_xor(a, 4, 64);
    a += __shfl_xor(a, 8, 64);
    a += __shfl_xor(a, 16, 64);
    a += __shfl_xor(a, 32, 64);
    if (j == 0) out[b * 2 + o] = a + f2b[o];
  }
}

extern "C" void kernel_launch(void* const* d_in, const int* in_sizes, int n_in,
                              void* d_out, int out_size, void* d_ws,
                              size_t ws_size, hipStream_t stream) {
  const int* x = (const int*)d_in[0];
  const float* embt = (const float*)d_in[1];
  const float* gcw = (const float*)d_in[2];
  const float* gcb = (const float*)d_in[3];
  const float* gbn = (const float*)d_in[4];
  const float* gf1w = (const float*)d_in[5];
  const float* gf1b = (const float*)d_in[6];
  const float* gf2w = (const float*)d_in[7];
  const float* gf2b = (const float*)d_in[8];
  const float* e1w = (const float*)d_in[9];
  const float* e1b = (const float*)d_in[10];
  const float* ebn1 = (const float*)d_in[11];
  const float* e2w = (const float*)d_in[12];
  const float* e2b = (const float*)d_in[13];
  const float* ebn2 = (const float*)d_in[14];
  const float* e3w = (const float*)d_in[15];
  const float* e3b = (const float*)d_in[16];
  const float* ebn3 = (const float*)d_in[17];
  const float* f1w = (const float*)d_in[18];
  const float* f1b = (const float*)d_in[19];
  const float* f2w = (const float*)d_in[20];
  const float* f2b = (const float*)d_in[21];
  float* out = (float*)d_out;

  const int B = in_sizes[0] / 60;  // 16384

  transpose_w_kernel<<<(47616 + 255) / 256, 256, 0, stream>>>(gcw, e2w, e3w,
                                                              ebn2, ebn3);
  build_p_kernel<<<(50064 + 255) / 256, 256, 0, stream>>>(
      embt, gcw, e1w, gbn, gcb, ebn1, e1b, ebn2, e2b, ebn3, e3b);
  moe_fused_kernel<<<B, 256, 0, stream>>>(x, embt, gcb, gbn, gf1w, gf1b, gf2w,
                                          gf2b, f1w, f1b, f2w, f2b, out);
}

// Round 18
// 318.278 us; speedup vs baseline: 4.2489x; 4.0784x over previous
//
#include <hip/hip_runtime.h>
#include <math.h>

#define BN_EPS 1e-5f

typedef float v2f __attribute__((ext_vector_type(2)));

// Exact-path transposed weights [ci][t][co]. g_wgT is UNSCALED (bit-exact
// gating fallback). Expert conv2/3 weights carry the BN scale folded in.
__device__ __align__(16) float g_wgT[24576 + 192];  // gating conv1 (fallback)
__device__ __align__(16) float g_we2T[18432 + 96];  // expert conv2 (xBN scale)
__device__ __align__(16) float g_we3T[4608 + 48];   // expert conv3 (xBN scale)

// fp32 token-indexed conv1 tables with BN FOLDED IN (scale on all planes,
// bias on the t=1 plane). Layout [t][v][64ch], v=64 row = zeros (pad edges).
__device__ __align__(16) float g_Pf[12480];   // gating  [3][65][64]
__device__ __align__(16) float e_Pf[37440];   // experts [3][3][65][64]
__device__ float c2_add[96], c3_add[48];

__global__ __launch_bounds__(256) void transpose_w_kernel(
    const float* __restrict__ gw, const float* __restrict__ e2w,
    const float* __restrict__ e3w, const float* __restrict__ ebn2,
    const float* __restrict__ ebn3) {
  int idx = blockIdx.x * 256 + threadIdx.x;
  if (idx < 24576) {
    int co = idx & 63, r = idx >> 6;
    int t = r % 3, ci = r / 3;
    g_wgT[idx] = gw[(co * 128 + ci) * 3 + t];
  } else if (idx < 24576 + 18432) {
    int jj = idx - 24576;
    int e = jj / 6144, j = jj % 6144;
    int co = j & 31, r = j >> 5;
    int t = r % 3, ci = r / 3;
    const float* bn = ebn2 + e * 128;
    float inv = bn[co] / sqrtf(bn[96 + co] + BN_EPS);
    g_we2T[jj] = e2w[e * 6144 + (co * 64 + ci) * 3 + t] * inv;
  } else if (idx < 24576 + 18432 + 4608) {
    int jj = idx - (24576 + 18432);
    int e = jj / 1536, j = jj % 1536;
    int co = j & 15, r = j >> 4;
    int t = r % 3, ci = r / 3;
    const float* bn = ebn3 + e * 64;
    float inv = bn[co] / sqrtf(bn[48 + co] + BN_EPS);
    g_we3T[jj] = e3w[e * 1536 + (co * 32 + ci) * 3 + t] * inv;
  }
}

__global__ __launch_bounds__(256) void build_p_kernel(
    const float* __restrict__ embt, const float* __restrict__ gw,
    const float* __restrict__ e1w, const float* __restrict__ gbn,
    const float* __restrict__ gcb, const float* __restrict__ ebn1,
    const float* __restrict__ e1b, const float* __restrict__ ebn2,
    const float* __restrict__ e2b, const float* __restrict__ ebn3,
    const float* __restrict__ e3b) {
  int idx = blockIdx.x * 256 + threadIdx.x;
  if (idx < 12480) {
    int co = idx & 63, r = idx >> 6;
    int v = r % 65, t = r / 65;
    float a = 0.f;
    if (v < 64) {
      float dot = 0.f;
#pragma unroll 8
      for (int ci = 0; ci < 128; ++ci)
        dot = fmaf(embt[v * 128 + ci], gw[(co * 128 + ci) * 3 + t], dot);
      float inv = gbn[co] / sqrtf(gbn[192 + co] + BN_EPS);
      float add = gbn[64 + co] + (gcb[co] - gbn[128 + co]) * inv;
      a = (t == 1) ? fmaf(dot, inv, add) : dot * inv;
    }
    g_Pf[idx] = a;
  } else if (idx < 12480 + 37440) {
    int j = idx - 12480;
    int co = j & 63, r = j >> 6;
    int v = r % 65, tt = r / 65;
    int t = tt % 3, e = tt / 3;
    float a = 0.f;
    if (v < 64) {
      float dot = 0.f;
#pragma unroll 8
      for (int ci = 0; ci < 128; ++ci)
        dot = fmaf(embt[v * 128 + ci],
                   e1w[e * 24576 + (co * 128 + ci) * 3 + t], dot);
      const float* bn = ebn1 + e * 256;
      float inv = bn[co] / sqrtf(bn[192 + co] + BN_EPS);
      float add = bn[64 + co] + (e1b[e * 64 + co] - bn[128 + co]) * inv;
      a = (t == 1) ? fmaf(dot, inv, add) : dot * inv;
    }
    e_Pf[j] = a;
  } else if (idx < 12480 + 37440 + 144) {
    int q = idx - (12480 + 37440);
    if (q < 96) {
      int e = q >> 5, co = q & 31;
      const float* bn = ebn2 + e * 128;
      float inv = bn[co] / sqrtf(bn[96 + co] + BN_EPS);
      c2_add[q] = bn[32 + co] + (e2b[e * 32 + co] - bn[64 + co]) * inv;
    } else {
      int j = q - 96;
      int e = j >> 4, co = j & 15;
      const float* bn = ebn3 + e * 64;
      float inv = bn[co] / sqrtf(bn[48 + co] + BN_EPS);
      c3_add[j] = bn[16 + co] + (e3b[e * 16 + co] - bn[32 + co]) * inv;
    }
  }
}

// ---- exact conv (bit-matches np, fallback only): 3 LDS reads/ci ----
template <int CIN, int CO, int NCO>
__device__ __forceinline__ void convG(const float* __restrict__ wT,
                                      const float* E, int l,
                                      v2f (&acc)[NCO / 2]) {
#pragma unroll 4
  for (int ci = 0; ci < CIN; ++ci) {
    const float* row = E + ci * 64 + l;
    float e0 = row[0], e1 = row[1], e2 = row[2];
    v2f e0v = {e0, e0}, e1v = {e1, e1}, e2v = {e2, e2};
    const float* wrow = wT + ci * (3 * CO);
#pragma unroll
    for (int k2 = 0; k2 < NCO / 2; ++k2) {
      v2f w0 = *reinterpret_cast<const v2f*>(wrow + 2 * k2);
      v2f w1 = *reinterpret_cast<const v2f*>(wrow + CO + 2 * k2);
      v2f w2 = *reinterpret_cast<const v2f*>(wrow + 2 * CO + 2 * k2);
      acc[k2] = __builtin_elementwise_fma(
          e0v, w0,
          __builtin_elementwise_fma(
              e1v, w1, __builtin_elementwise_fma(e2v, w2, acc[k2])));
    }
  }
}

// ---- scatter conv: 1 LDS read/ci into 3 banks; combine via shuffles ----
template <int CIN, int CO, int NCO>
__device__ __forceinline__ void convA(const float* __restrict__ wT,
                                      const float* E, int l,
                                      v2f (&A0)[NCO / 2], v2f (&A1)[NCO / 2],
                                      v2f (&A2)[NCO / 2]) {
#pragma unroll 2
  for (int ci = 0; ci < CIN; ++ci) {
    float r = E[ci * 64 + l];
    v2f rv = {r, r};
    const float* wrow = wT + ci * (3 * CO);
#pragma unroll
    for (int k2 = 0; k2 < NCO / 2; ++k2) {
      v2f w0 = *reinterpret_cast<const v2f*>(wrow + 2 * k2);
      v2f w1 = *reinterpret_cast<const v2f*>(wrow + CO + 2 * k2);
      v2f w2 = *reinterpret_cast<const v2f*>(wrow + 2 * CO + 2 * k2);
      A0[k2] = __builtin_elementwise_fma(rv, w0, A0[k2]);
      A1[k2] = __builtin_elementwise_fma(rv, w1, A1[k2]);
      A2[k2] = __builtin_elementwise_fma(rv, w2, A2[k2]);
    }
  }
}

__global__ __launch_bounds__(256, 8) void moe_fused_kernel(
    const int* __restrict__ x, const float* __restrict__ embt,
    const float* __restrict__ gcb, const float* __restrict__ gbn,
    const float* __restrict__ gf1w, const float* __restrict__ gf1b,
    const float* __restrict__ gf2w, const float* __restrict__ gf2b,
    const float* __restrict__ f1w, const float* __restrict__ f1b,
    const float* __restrict__ f2w, const float* __restrict__ f2b,
    float* __restrict__ out) {
  // smem layout (phased aliasing):
  // [0,4160)    gating Gbuf[64][65]  ->  Bbuf[64][64] (expert) at [0,4096)
  //             fallback: tileF [0,2048) + TbufF [2048,4028)
  //             conv3 staging Cbuf[60][17] at [2048,3068)
  // [4160,4416) Pbuf partials (256)
  // [4416,...)  hbuf64 h2buf32 glog4 mbuf16 o64
  __shared__ __align__(16) float smem[4608];
  float* Bbuf = smem;
  float* Gbuf = smem;
  float* Cbuf = smem + 2048;
  float* Pbuf = smem + 4160;
  float* hbuf = smem + 4416;
  float* h2buf = smem + 4480;
  float* glog = smem + 4512;
  float* mbuf = smem + 4516;
  float* o64 = smem + 4532;
  __shared__ int toks[64];
  __shared__ int selbuf, fbflag;

  const int b = blockIdx.x;
  const int tid = threadIdx.x;
  const int lane = tid & 63;
  const int wv = tid >> 6;
  const int wvu = __builtin_amdgcn_readfirstlane(wv);
  const bool valid = (lane < 60);
  const int cob = wvu * 16;
  const int wcol = (lane == 63) ? 0 : lane + 1;  // clean-write col mapping

  if (tid < 64) toks[tid] = x[b * 60 + (tid < 60 ? tid : 59)];
  __syncthreads();

  // s[k] = conv1 post-BN pre-relu value for co=cob+k at position lane.
  // fp32 tables, BN folded (scale everywhere, bias on t=1 plane).
  auto table_sum = [&](const float* __restrict__ P, float(&s)[16]) {
    const int l = lane;
    const int v0 = l ? toks[l - 1] : 64;
    const int v1 = toks[l];
    const int v2 = (l < 59) ? toks[l + 1] : 64;
    const float4* r0 = reinterpret_cast<const float4*>(P + v0 * 64 + cob);
    const float4* r1 =
        reinterpret_cast<const float4*>(P + 4160 + v1 * 64 + cob);
    const float4* r2 =
        reinterpret_cast<const float4*>(P + 8320 + v2 * 64 + cob);
#pragma unroll
    for (int q = 0; q < 4; ++q) {
      float4 a0 = r0[q], a1 = r1[q], a2 = r2[q];
      s[4 * q + 0] = (a1.x + a0.x) + a2.x;
      s[4 * q + 1] = (a1.y + a0.y) + a2.y;
      s[4 * q + 2] = (a1.z + a0.z) + a2.z;
      s[4 * q + 3] = (a1.w + a0.w) + a2.w;
    }
  };

  // ---- gating conv1 (table, BN folded) + ReLU -> Gbuf[pos][ch] ----
  {
    float s[16];
    table_sum(g_Pf, s);
#pragma unroll
    for (int k = 0; k < 16; ++k) {
      float v = valid ? fmaxf(s[k], 0.f) : 0.f;
      Gbuf[lane * 65 + cob + k] = v;
    }
  }
  __syncthreads();
  // max over L: 256 threads, (channel, 15-position strip) each
  {
    const int ch = tid & 63, q = tid >> 6;
    const float* col = Gbuf + (q * 15) * 65 + ch;
    float m = col[0];
#pragma unroll
    for (int i = 1; i < 15; ++i) m = fmaxf(m, col[i * 65]);
    Pbuf[q * 64 + ch] = m;
  }
  __syncthreads();
  if (tid < 64)
    hbuf[tid] = fmaxf(fmaxf(Pbuf[tid], Pbuf[64 + tid]),
                      fmaxf(Pbuf[128 + tid], Pbuf[192 + tid]));
  __syncthreads();

  // ---- gating MLP 64->32 (parallel tree) ----
  {
    const int o = tid >> 3, p = tid & 7;
    const float* wrow = gf1w + o * 64 + p * 8;
    float4 wa = reinterpret_cast<const float4*>(wrow)[0];
    float4 wb = reinterpret_cast<const float4*>(wrow)[1];
    const float* hh = hbuf + p * 8;
    float a = 0.f;
    a = fmaf(hh[0], wa.x, a);
    a = fmaf(hh[1], wa.y, a);
    a = fmaf(hh[2], wa.z, a);
    a = fmaf(hh[3], wa.w, a);
    a = fmaf(hh[4], wb.x, a);
    a = fmaf(hh[5], wb.y, a);
    a = fmaf(hh[6], wb.z, a);
    a = fmaf(hh[7], wb.w, a);
    a += __shfl_xor(a, 1, 64);
    a += __shfl_xor(a, 2, 64);
    a += __shfl_xor(a, 4, 64);
    if (p == 0) h2buf[o] = fmaxf(a + gf1b[o], 0.f);
  }
  __syncthreads();
  // ---- 32->3 (parallel across 96 lanes, 32-lane tree reduce) ----
  if (tid < 96) {
    const int o = tid >> 5, j = tid & 31;
    float a = h2buf[j] * gf2w[o * 32 + j];
    a += __shfl_xor(a, 1, 32);
    a += __shfl_xor(a, 2, 32);
    a += __shfl_xor(a, 4, 32);
    a += __shfl_xor(a, 8, 32);
    a += __shfl_xor(a, 16, 32);
    if (j == 0) glog[o] = a + gf2b[o];
  }
  __syncthreads();
  if (tid == 0) {
    int best = 0;
    float bv = glog[0];
    if (glog[1] > bv) { bv = glog[1]; best = 1; }
    if (glog[2] > bv) { bv = glog[2]; best = 2; }
    float second = -1e30f;
#pragma unroll
    for (int i = 0; i < 3; ++i)
      if (i != best) second = fmaxf(second, glog[i]);
    selbuf = best;
    fbflag = (bv - second < 2e-4f) ? 1 : 0;  // >> fp32-table logit error
  }
  __syncthreads();

  if (fbflag) {
    // rare near-tie: recompute gating bit-exactly (convG + exact BN + serial
    // shuffle-max + serial MLP, proven absmax==0 vs np) and re-derive argmax.
    float* tileF = smem;          // [0,2048); Gbuf dead now
    float* TbufF = smem + 2048;   // 60*33 staging
    if (tid < 128) {
      int r = tid >> 2;
      const int ctab[4] = {0, 61, 62, 63};
      tileF[r * 64 + ctab[tid & 3]] = 0.f;
    }
    v2f acc[8] = {};
    for (int tile = 0; tile < 4; ++tile) {
      for (int i = tid; i < 60 * 32; i += 256) {
        int l = i >> 5, dp = i & 31;
        TbufF[l * 33 + dp] = embt[toks[l] * 128 + tile * 32 + dp];
      }
      __syncthreads();
      if (valid) {
#pragma unroll
        for (int dp = wvu; dp < 32; dp += 4)
          tileF[dp * 64 + lane + 1] = TbufF[lane * 33 + dp];
      }
      __syncthreads();
      convG<32, 64, 16>(g_wgT + tile * 32 * 192 + cob, tileF, lane, acc);
      __syncthreads();
    }
#pragma unroll
    for (int k = 0; k < 16; ++k) {
      int co = cob + k;
      float inv = gbn[co] / sqrtf(gbn[192 + co] + BN_EPS);
      float add = gbn[64 + co] + (gcb[co] - gbn[128 + co]) * inv;
      float v = valid ? fmaxf(fmaf(acc[k >> 1][k & 1], inv, add), 0.f) : 0.f;
#pragma unroll
      for (int off = 1; off < 64; off <<= 1)
        v = fmaxf(v, __shfl_xor(v, off, 64));
      if (lane == 0) hbuf[co] = v;
    }
    __syncthreads();
    if (tid < 32) {
      float a = gf1b[tid];
#pragma unroll 8
      for (int k = 0; k < 64; ++k) a = fmaf(hbuf[k], gf1w[tid * 64 + k], a);
      h2buf[tid] = fmaxf(a, 0.f);
    }
    __syncthreads();
    if (tid < 3) {
      float a = gf2b[tid];
#pragma unroll 8
      for (int k = 0; k < 32; ++k) a = fmaf(h2buf[k], gf2w[tid * 32 + k], a);
      glog[tid] = a;
    }
    __syncthreads();
    if (tid == 0) {
      int best = 0;
      float bv = glog[0];
      if (glog[1] > bv) { bv = glog[1]; best = 1; }
      if (glog[2] > bv) { best = 2; }
      selbuf = best;
    }
    __syncthreads();
  }
  const int e = __builtin_amdgcn_readfirstlane(selbuf);

  // ---- expert conv1 (table, BN folded) -> Bbuf ----
  {
    float s[16];
    table_sum(e_Pf + e * 12480, s);
#pragma unroll
    for (int k = 0; k < 16; ++k) {
      float vv = fmaxf(s[k], 0.f);
      Bbuf[(cob + k) * 64 + wcol] = valid ? vv : 0.f;
    }
  }
  __syncthreads();

  // ---- expert conv2 (scatter, scale-in-weights): Bbuf -> Bbuf rows 0..31 ----
  {
    v2f A0[4] = {}, A1[4] = {}, A2[4] = {};
    const int cob2 = wvu * 8;
    convA<64, 32, 8>(g_we2T + e * 6144 + cob2, Bbuf, lane, A0, A1, A2);
    float val8[8];
#pragma unroll
    for (int k = 0; k < 8; ++k) {
      int co = cob2 + k;
      float a1 = __shfl(A1[k >> 1][k & 1], lane + 1, 64);
      float a2 = __shfl(A2[k >> 1][k & 1], lane + 2, 64);
      float ss = (A0[k >> 1][k & 1] + a1) + a2;
      float vv = fmaxf(ss + c2_add[e * 32 + co], 0.f);
      val8[k] = valid ? vv : 0.f;
    }
    __syncthreads();  // all Bbuf reads done before overwrite
#pragma unroll
    for (int k = 0; k < 8; ++k) Bbuf[(cob2 + k) * 64 + wcol] = val8[k];
  }
  __syncthreads();

  // ---- expert conv3 (scatter) + ReLU -> Cbuf[pos][ch] (stride 17) ----
  {
    v2f A0[2] = {}, A1[2] = {}, A2[2] = {};
    const int cob3 = wvu * 4;
    convA<32, 16, 4>(g_we3T + e * 1536 + cob3, Bbuf, lane, A0, A1, A2);
#pragma unroll
    for (int k = 0; k < 4; ++k) {
      int co = cob3 + k;
      float a1 = __shfl(A1[k >> 1][k & 1], lane + 1, 64);
      float a2 = __shfl(A2[k >> 1][k & 1], lane + 2, 64);
      float ss = (A0[k >> 1][k & 1] + a1) + a2;
      float v = fmaxf(ss + c3_add[e * 16 + co], 0.f);
      if (valid) Cbuf[lane * 17 + co] = v;
    }
  }
  __syncthreads();
  // max over L: 64 threads, (channel, 15-position strip)
  if (tid < 64) {
    const int ch = tid & 15, q = tid >> 4;
    const float* col = Cbuf + (q * 15) * 17 + ch;
    float m = col[0];
#pragma unroll
    for (int i = 1; i < 15; ++i) m = fmaxf(m, col[i * 17]);
    Pbuf[q * 16 + ch] = m;
  }
  __syncthreads();
  if (tid < 16)
    mbuf[tid] = fmaxf(fmaxf(Pbuf[tid], Pbuf[16 + tid]),
                      fmaxf(Pbuf[32 + tid], Pbuf[48 + tid]));
  __syncthreads();

  // ---- head MLP 16->64->2 ----
  if (tid < 64) {
    float a = f1b[tid];
#pragma unroll
    for (int k = 0; k < 16; ++k) a = fmaf(mbuf[k], f1w[tid * 16 + k], a);
    o64[tid] = fmaxf(a, 0.f);
  }
  __syncthreads();
  if (tid < 128) {
    const int o = tid >> 6, j = tid & 63;
    float a = o64[j] * f2w[o * 64 + j];
    a += __shfl_xor(a, 1, 64);
    a += __shfl_xor(a, 2, 64);
    a += __shfl_xor(a, 4, 64);
    a += __shfl_xor(a, 8, 64);
    a += __shfl_xor(a, 16, 64);
    a += __shfl_xor(a, 32, 64);
    if (j == 0) out[b * 2 + o] = a + f2b[o];
  }
}

extern "C" void kernel_launch(void* const* d_in, const int* in_sizes, int n_in,
                              void* d_out, int out_size, void* d_ws,
                              size_t ws_size, hipStream_t stream) {
  const int* x = (const int*)d_in[0];
  const float* embt = (const float*)d_in[1];
  const float* gcw = (const float*)d_in[2];
  const float* gcb = (const float*)d_in[3];
  const float* gbn = (const float*)d_in[4];
  const float* gf1w = (const float*)d_in[5];
  const float* gf1b = (const float*)d_in[6];
  const float* gf2w = (const float*)d_in[7];
  const float* gf2b = (const float*)d_in[8];
  const float* e1w = (const float*)d_in[9];
  const float* e1b = (const float*)d_in[10];
  const float* ebn1 = (const float*)d_in[11];
  const float* e2w = (const float*)d_in[12];
  const float* e2b = (const float*)d_in[13];
  const float* ebn2 = (const float*)d_in[14];
  const float* e3w = (const float*)d_in[15];
  const float* e3b = (const float*)d_in[16];
  const float* ebn3 = (const float*)d_in[17];
  const float* f1w = (const float*)d_in[18];
  const float* f1b = (const float*)d_in[19];
  const float* f2w = (const float*)d_in[20];
  const float* f2b = (const float*)d_in[21];
  float* out = (float*)d_out;

  const int B = in_sizes[0] / 60;  // 16384

  transpose_w_kernel<<<(47616 + 255) / 256, 256, 0, stream>>>(gcw, e2w, e3w,
                                                              ebn2, ebn3);
  build_p_kernel<<<(50064 + 255) / 256, 256, 0, stream>>>(
      embt, gcw, e1w, gbn, gcb, ebn1, e1b, ebn2, e2b, ebn3, e3b);
  moe_fused_kernel<<<B, 256, 0, stream>>>(x, embt, gcb, gbn, gf1w, gf1b, gf2w,
                                          gf2b, f1w, f1b, f2w, f2b, out);
}

// Round 19
// 316.907 us; speedup vs baseline: 4.2673x; 1.0043x over previous
//
#include <hip/hip_runtime.h>
#include <math.h>

#define BN_EPS 1e-5f

typedef float v2f __attribute__((ext_vector_type(2)));

// Exact-path transposed weights [ci][t][co]. g_wgT is UNSCALED (bit-exact
// gating fallback). Expert conv2/3 weights carry the BN scale folded in.
__device__ __align__(16) float g_wgT[24576 + 192];  // gating conv1 (fallback)
__device__ __align__(16) float g_we2T[18432 + 96];  // expert conv2 (xBN scale)
__device__ __align__(16) float g_we3T[4608 + 48];   // expert conv3 (xBN scale)

// fp32 token-indexed conv1 tables with BN FOLDED IN (scale on all planes,
// bias on the t=1 plane). Layout [t][v][64ch], v=64 row = zeros (pad edges).
__device__ __align__(16) float g_Pf[12480];   // gating  [3][65][64]
__device__ __align__(16) float e_Pf[37440];   // experts [3][3][65][64]
__device__ float c2_add[96], c3_add[48];

__global__ __launch_bounds__(256) void transpose_w_kernel(
    const float* __restrict__ gw, const float* __restrict__ e2w,
    const float* __restrict__ e3w, const float* __restrict__ ebn2,
    const float* __restrict__ ebn3) {
  int idx = blockIdx.x * 256 + threadIdx.x;
  if (idx < 24576) {
    int co = idx & 63, r = idx >> 6;
    int t = r % 3, ci = r / 3;
    g_wgT[idx] = gw[(co * 128 + ci) * 3 + t];
  } else if (idx < 24576 + 18432) {
    int jj = idx - 24576;
    int e = jj / 6144, j = jj % 6144;
    int co = j & 31, r = j >> 5;
    int t = r % 3, ci = r / 3;
    const float* bn = ebn2 + e * 128;
    float inv = bn[co] / sqrtf(bn[96 + co] + BN_EPS);
    g_we2T[jj] = e2w[e * 6144 + (co * 64 + ci) * 3 + t] * inv;
  } else if (idx < 24576 + 18432 + 4608) {
    int jj = idx - (24576 + 18432);
    int e = jj / 1536, j = jj % 1536;
    int co = j & 15, r = j >> 4;
    int t = r % 3, ci = r / 3;
    const float* bn = ebn3 + e * 64;
    float inv = bn[co] / sqrtf(bn[48 + co] + BN_EPS);
    g_we3T[jj] = e3w[e * 1536 + (co * 32 + ci) * 3 + t] * inv;
  }
}

__global__ __launch_bounds__(256) void build_p_kernel(
    const float* __restrict__ embt, const float* __restrict__ gw,
    const float* __restrict__ e1w, const float* __restrict__ gbn,
    const float* __restrict__ gcb, const float* __restrict__ ebn1,
    const float* __restrict__ e1b, const float* __restrict__ ebn2,
    const float* __restrict__ e2b, const float* __restrict__ ebn3,
    const float* __restrict__ e3b) {
  int idx = blockIdx.x * 256 + threadIdx.x;
  if (idx < 12480) {
    int co = idx & 63, r = idx >> 6;
    int v = r % 65, t = r / 65;
    float a = 0.f;
    if (v < 64) {
      float dot = 0.f;
#pragma unroll 8
      for (int ci = 0; ci < 128; ++ci)
        dot = fmaf(embt[v * 128 + ci], gw[(co * 128 + ci) * 3 + t], dot);
      float inv = gbn[co] / sqrtf(gbn[192 + co] + BN_EPS);
      float add = gbn[64 + co] + (gcb[co] - gbn[128 + co]) * inv;
      a = (t == 1) ? fmaf(dot, inv, add) : dot * inv;
    }
    g_Pf[idx] = a;
  } else if (idx < 12480 + 37440) {
    int j = idx - 12480;
    int co = j & 63, r = j >> 6;
    int v = r % 65, tt = r / 65;
    int t = tt % 3, e = tt / 3;
    float a = 0.f;
    if (v < 64) {
      float dot = 0.f;
#pragma unroll 8
      for (int ci = 0; ci < 128; ++ci)
        dot = fmaf(embt[v * 128 + ci],
                   e1w[e * 24576 + (co * 128 + ci) * 3 + t], dot);
      const float* bn = ebn1 + e * 256;
      float inv = bn[co] / sqrtf(bn[192 + co] + BN_EPS);
      float add = bn[64 + co] + (e1b[e * 64 + co] - bn[128 + co]) * inv;
      a = (t == 1) ? fmaf(dot, inv, add) : dot * inv;
    }
    e_Pf[j] = a;
  } else if (idx < 12480 + 37440 + 144) {
    int q = idx - (12480 + 37440);
    if (q < 96) {
      int e = q >> 5, co = q & 31;
      const float* bn = ebn2 + e * 128;
      float inv = bn[co] / sqrtf(bn[96 + co] + BN_EPS);
      c2_add[q] = bn[32 + co] + (e2b[e * 32 + co] - bn[64 + co]) * inv;
    } else {
      int j = q - 96;
      int e = j >> 4, co = j & 15;
      const float* bn = ebn3 + e * 64;
      float inv = bn[co] / sqrtf(bn[48 + co] + BN_EPS);
      c3_add[j] = bn[16 + co] + (e3b[e * 16 + co] - bn[32 + co]) * inv;
    }
  }
}

// ---- exact conv (bit-matches np, fallback only): 3 LDS reads/ci ----
template <int CIN, int CO, int NCO>
__device__ __forceinline__ void convG(const float* __restrict__ wT,
                                      const float* E, int l,
                                      v2f (&acc)[NCO / 2]) {
#pragma unroll 4
  for (int ci = 0; ci < CIN; ++ci) {
    const float* row = E + ci * 64 + l;
    float e0 = row[0], e1 = row[1], e2 = row[2];
    v2f e0v = {e0, e0}, e1v = {e1, e1}, e2v = {e2, e2};
    const float* wrow = wT + ci * (3 * CO);
#pragma unroll
    for (int k2 = 0; k2 < NCO / 2; ++k2) {
      v2f w0 = *reinterpret_cast<const v2f*>(wrow + 2 * k2);
      v2f w1 = *reinterpret_cast<const v2f*>(wrow + CO + 2 * k2);
      v2f w2 = *reinterpret_cast<const v2f*>(wrow + 2 * CO + 2 * k2);
      acc[k2] = __builtin_elementwise_fma(
          e0v, w0,
          __builtin_elementwise_fma(
              e1v, w1, __builtin_elementwise_fma(e2v, w2, acc[k2])));
    }
  }
}

// ---- scatter conv: 1 LDS read/ci into 3 banks; combine via shuffles ----
template <int CIN, int CO, int NCO>
__device__ __forceinline__ void convA(const float* __restrict__ wT,
                                      const float* E, int l,
                                      v2f (&A0)[NCO / 2], v2f (&A1)[NCO / 2],
                                      v2f (&A2)[NCO / 2]) {
#pragma unroll 2
  for (int ci = 0; ci < CIN; ++ci) {
    float r = E[ci * 64 + l];
    v2f rv = {r, r};
    const float* wrow = wT + ci * (3 * CO);
#pragma unroll
    for (int k2 = 0; k2 < NCO / 2; ++k2) {
      v2f w0 = *reinterpret_cast<const v2f*>(wrow + 2 * k2);
      v2f w1 = *reinterpret_cast<const v2f*>(wrow + CO + 2 * k2);
      v2f w2 = *reinterpret_cast<const v2f*>(wrow + 2 * CO + 2 * k2);
      A0[k2] = __builtin_elementwise_fma(rv, w0, A0[k2]);
      A1[k2] = __builtin_elementwise_fma(rv, w1, A1[k2]);
      A2[k2] = __builtin_elementwise_fma(rv, w2, A2[k2]);
    }
  }
}

__global__ __launch_bounds__(256, 8) void moe_fused_kernel(
    const int* __restrict__ x, const float* __restrict__ embt,
    const float* __restrict__ gcb, const float* __restrict__ gbn,
    const float* __restrict__ gf1w, const float* __restrict__ gf1b,
    const float* __restrict__ gf2w, const float* __restrict__ gf2b,
    const float* __restrict__ f1w, const float* __restrict__ f1b,
    const float* __restrict__ f2w, const float* __restrict__ f2b,
    float* __restrict__ out) {
  // smem layout (phased aliasing):
  // [0,4160)    gating Gbuf[64][65]  ->  Bbuf[64][64] (expert) at [0,4096)
  //             fallback: tileF [0,2048) + TbufF [2048,4028)
  //             conv3 staging Cbuf[60][17] at [2048,3068)
  // [4160,4416) Pbuf partials (256)
  // [4416,...)  hbuf64 h2buf32 glog4 mbuf16
  __shared__ __align__(16) float smem[4608];
  float* Bbuf = smem;
  float* Gbuf = smem;
  float* Cbuf = smem + 2048;
  float* Pbuf = smem + 4160;
  float* hbuf = smem + 4416;
  float* h2buf = smem + 4480;
  float* glog = smem + 4512;
  float* mbuf = smem + 4516;
  __shared__ int selbuf, fbflag;

  const int b = blockIdx.x;
  const int tid = threadIdx.x;
  const int lane = tid & 63;
  const int wv = tid >> 6;
  const int wvu = __builtin_amdgcn_readfirstlane(wv);
  const bool valid = (lane < 60);
  const int cob = wvu * 16;
  const int wcol = (lane == 63) ? 0 : lane + 1;  // clean-write col mapping

  // per-lane token indices, held in registers for both table lookups
  // (v==64 selects the zero row of the tables — exact pad handling)
  const int xbase = b * 60;
  const int v0r = lane ? x[xbase + (lane < 60 ? lane - 1 : 58)] : 64;
  const int v1r = x[xbase + (lane < 60 ? lane : 59)];
  const int v2r = (lane < 59) ? x[xbase + lane + 1] : 64;

  // s[k] = conv1 post-BN pre-relu value for co=cob+k at position lane.
  auto table_sum = [&](const float* __restrict__ P, float(&s)[16]) {
    const float4* r0 = reinterpret_cast<const float4*>(P + v0r * 64 + cob);
    const float4* r1 =
        reinterpret_cast<const float4*>(P + 4160 + v1r * 64 + cob);
    const float4* r2 =
        reinterpret_cast<const float4*>(P + 8320 + v2r * 64 + cob);
#pragma unroll
    for (int q = 0; q < 4; ++q) {
      float4 a0 = r0[q], a1 = r1[q], a2 = r2[q];
      s[4 * q + 0] = (a1.x + a0.x) + a2.x;
      s[4 * q + 1] = (a1.y + a0.y) + a2.y;
      s[4 * q + 2] = (a1.z + a0.z) + a2.z;
      s[4 * q + 3] = (a1.w + a0.w) + a2.w;
    }
  };

  // ---- gating conv1 (table, BN folded) + ReLU -> Gbuf[pos][ch] ----
  {
    float s[16];
    table_sum(g_Pf, s);
#pragma unroll
    for (int k = 0; k < 16; ++k) {
      float v = valid ? fmaxf(s[k], 0.f) : 0.f;
      Gbuf[lane * 65 + cob + k] = v;
    }
  }
  __syncthreads();
  // max over L: 256 threads, (channel, 15-position strip) each
  {
    const int ch = tid & 63, q = tid >> 6;
    const float* col = Gbuf + (q * 15) * 65 + ch;
    float m = col[0];
#pragma unroll
    for (int i = 1; i < 15; ++i) m = fmaxf(m, col[i * 65]);
    Pbuf[q * 64 + ch] = m;
  }
  __syncthreads();
  if (tid < 64)
    hbuf[tid] = fmaxf(fmaxf(Pbuf[tid], Pbuf[64 + tid]),
                      fmaxf(Pbuf[128 + tid], Pbuf[192 + tid]));
  __syncthreads();

  // ---- gating MLP 64->32 (parallel tree) ----
  {
    const int o = tid >> 3, p = tid & 7;
    const float* wrow = gf1w + o * 64 + p * 8;
    float4 wa = reinterpret_cast<const float4*>(wrow)[0];
    float4 wb = reinterpret_cast<const float4*>(wrow)[1];
    const float* hh = hbuf + p * 8;
    float a = 0.f;
    a = fmaf(hh[0], wa.x, a);
    a = fmaf(hh[1], wa.y, a);
    a = fmaf(hh[2], wa.z, a);
    a = fmaf(hh[3], wa.w, a);
    a = fmaf(hh[4], wb.x, a);
    a = fmaf(hh[5], wb.y, a);
    a = fmaf(hh[6], wb.z, a);
    a = fmaf(hh[7], wb.w, a);
    a += __shfl_xor(a, 1, 64);
    a += __shfl_xor(a, 2, 64);
    a += __shfl_xor(a, 4, 64);
    if (p == 0) h2buf[o] = fmaxf(a + gf1b[o], 0.f);
  }
  __syncthreads();
  // ---- 32->3 (parallel across 96 lanes, 32-lane tree reduce) ----
  if (tid < 96) {
    const int o = tid >> 5, j = tid & 31;
    float a = h2buf[j] * gf2w[o * 32 + j];
    a += __shfl_xor(a, 1, 32);
    a += __shfl_xor(a, 2, 32);
    a += __shfl_xor(a, 4, 32);
    a += __shfl_xor(a, 8, 32);
    a += __shfl_xor(a, 16, 32);
    if (j == 0) glog[o] = a + gf2b[o];
  }
  __syncthreads();
  if (tid == 0) {
    int best = 0;
    float bv = glog[0];
    if (glog[1] > bv) { bv = glog[1]; best = 1; }
    if (glog[2] > bv) { bv = glog[2]; best = 2; }
    float second = -1e30f;
#pragma unroll
    for (int i = 0; i < 3; ++i)
      if (i != best) second = fmaxf(second, glog[i]);
    selbuf = best;
    fbflag = (bv - second < 2e-4f) ? 1 : 0;  // >> fp32-table logit error
  }
  __syncthreads();

  if (fbflag) {
    // rare near-tie: recompute gating bit-exactly (convG + exact BN + serial
    // shuffle-max + serial MLP, proven absmax==0 vs np) and re-derive argmax.
    float* tileF = smem;          // [0,2048); Gbuf dead now
    float* TbufF = smem + 2048;   // 60*33 staging
    if (tid < 128) {
      int r = tid >> 2;
      const int ctab[4] = {0, 61, 62, 63};
      tileF[r * 64 + ctab[tid & 3]] = 0.f;
    }
    v2f acc[8] = {};
    for (int tile = 0; tile < 4; ++tile) {
      for (int i = tid; i < 60 * 32; i += 256) {
        int l = i >> 5, dp = i & 31;
        TbufF[l * 33 + dp] = embt[x[xbase + l] * 128 + tile * 32 + dp];
      }
      __syncthreads();
      if (valid) {
#pragma unroll
        for (int dp = wvu; dp < 32; dp += 4)
          tileF[dp * 64 + lane + 1] = TbufF[lane * 33 + dp];
      }
      __syncthreads();
      convG<32, 64, 16>(g_wgT + tile * 32 * 192 + cob, tileF, lane, acc);
      __syncthreads();
    }
#pragma unroll
    for (int k = 0; k < 16; ++k) {
      int co = cob + k;
      float inv = gbn[co] / sqrtf(gbn[192 + co] + BN_EPS);
      float add = gbn[64 + co] + (gcb[co] - gbn[128 + co]) * inv;
      float v = valid ? fmaxf(fmaf(acc[k >> 1][k & 1], inv, add), 0.f) : 0.f;
#pragma unroll
      for (int off = 1; off < 64; off <<= 1)
        v = fmaxf(v, __shfl_xor(v, off, 64));
      if (lane == 0) hbuf[co] = v;
    }
    __syncthreads();
    if (tid < 32) {
      float a = gf1b[tid];
#pragma unroll 8
      for (int k = 0; k < 64; ++k) a = fmaf(hbuf[k], gf1w[tid * 64 + k], a);
      h2buf[tid] = fmaxf(a, 0.f);
    }
    __syncthreads();
    if (tid < 3) {
      float a = gf2b[tid];
#pragma unroll 8
      for (int k = 0; k < 32; ++k) a = fmaf(h2buf[k], gf2w[tid * 32 + k], a);
      glog[tid] = a;
    }
    __syncthreads();
    if (tid == 0) {
      int best = 0;
      float bv = glog[0];
      if (glog[1] > bv) { bv = glog[1]; best = 1; }
      if (glog[2] > bv) { best = 2; }
      selbuf = best;
    }
    __syncthreads();
  }
  const int e = __builtin_amdgcn_readfirstlane(selbuf);

  // ---- expert conv1 (table, BN folded) -> Bbuf ----
  {
    float s[16];
    table_sum(e_Pf + e * 12480, s);
#pragma unroll
    for (int k = 0; k < 16; ++k) {
      float vv = fmaxf(s[k], 0.f);
      Bbuf[(cob + k) * 64 + wcol] = valid ? vv : 0.f;
    }
  }
  __syncthreads();

  // ---- expert conv2 (scatter, scale-in-weights): Bbuf -> Bbuf rows 0..31 ----
  {
    v2f A0[4] = {}, A1[4] = {}, A2[4] = {};
    const int cob2 = wvu * 8;
    convA<64, 32, 8>(g_we2T + e * 6144 + cob2, Bbuf, lane, A0, A1, A2);
    float val8[8];
#pragma unroll
    for (int k = 0; k < 8; ++k) {
      int co = cob2 + k;
      float a1 = __shfl(A1[k >> 1][k & 1], lane + 1, 64);
      float a2 = __shfl(A2[k >> 1][k & 1], lane + 2, 64);
      float ss = (A0[k >> 1][k & 1] + a1) + a2;
      float vv = fmaxf(ss + c2_add[e * 32 + co], 0.f);
      val8[k] = valid ? vv : 0.f;
    }
    __syncthreads();  // all Bbuf reads done before overwrite
#pragma unroll
    for (int k = 0; k < 8; ++k) Bbuf[(cob2 + k) * 64 + wcol] = val8[k];
  }
  __syncthreads();

  // ---- expert conv3 (scatter) + ReLU -> Cbuf[pos][ch] (stride 17) ----
  {
    v2f A0[2] = {}, A1[2] = {}, A2[2] = {};
    const int cob3 = wvu * 4;
    convA<32, 16, 4>(g_we3T + e * 1536 + cob3, Bbuf, lane, A0, A1, A2);
#pragma unroll
    for (int k = 0; k < 4; ++k) {
      int co = cob3 + k;
      float a1 = __shfl(A1[k >> 1][k & 1], lane + 1, 64);
      float a2 = __shfl(A2[k >> 1][k & 1], lane + 2, 64);
      float ss = (A0[k >> 1][k & 1] + a1) + a2;
      float v = fmaxf(ss + c3_add[e * 16 + co], 0.f);
      if (valid) Cbuf[lane * 17 + co] = v;
    }
  }
  __syncthreads();

  // ---- fused wave-0 tail: conv3-max + head MLP + output (no barriers;
  //      all LDS deps are same-wave, ordered by lgkmcnt) ----
  if (tid < 64) {
    // strip reduce: ch = tid&15, q = tid>>4, 15 positions each
    {
      const int ch = tid & 15, q = tid >> 4;
      const float* col = Cbuf + (q * 15) * 17 + ch;
      float m = col[0];
#pragma unroll
      for (int i = 1; i < 15; ++i) m = fmaxf(m, col[i * 17]);
      // combine across q (xor over lane bits 4,5 — same tree values as
      // the former Pbuf combine: max is associative/commutative)
      m = fmaxf(m, __shfl_xor(m, 16, 64));
      m = fmaxf(m, __shfl_xor(m, 32, 64));
      if (tid < 16) mbuf[tid] = m;
    }
    // o64 in registers (same-wave LDS read of mbuf; compiler orders)
    const int j = tid;
    float a = f1b[j];
#pragma unroll
    for (int k = 0; k < 16; ++k) a = fmaf(mbuf[k], f1w[j * 16 + k], a);
    const float o = fmaxf(a, 0.f);
    // final 2 logits: identical xor-tree to before
    float p0 = o * f2w[j];
    p0 += __shfl_xor(p0, 1, 64);
    p0 += __shfl_xor(p0, 2, 64);
    p0 += __shfl_xor(p0, 4, 64);
    p0 += __shfl_xor(p0, 8, 64);
    p0 += __shfl_xor(p0, 16, 64);
    p0 += __shfl_xor(p0, 32, 64);
    float p1 = o * f2w[64 + j];
    p1 += __shfl_xor(p1, 1, 64);
    p1 += __shfl_xor(p1, 2, 64);
    p1 += __shfl_xor(p1, 4, 64);
    p1 += __shfl_xor(p1, 8, 64);
    p1 += __shfl_xor(p1, 16, 64);
    p1 += __shfl_xor(p1, 32, 64);
    if (j == 0) {
      out[b * 2 + 0] = p0 + f2b[0];
      out[b * 2 + 1] = p1 + f2b[1];
    }
  }
}

extern "C" void kernel_launch(void* const* d_in, const int* in_sizes, int n_in,
                              void* d_out, int out_size, void* d_ws,
                              size_t ws_size, hipStream_t stream) {
  const int* x = (const int*)d_in[0];
  const float* embt = (const float*)d_in[1];
  const float* gcw = (const float*)d_in[2];
  const float* gcb = (const float*)d_in[3];
  const float* gbn = (const float*)d_in[4];
  const float* gf1w = (const float*)d_in[5];
  const float* gf1b = (const float*)d_in[6];
  const float* gf2w = (const float*)d_in[7];
  const float* gf2b = (const float*)d_in[8];
  const float* e1w = (const float*)d_in[9];
  const float* e1b = (const float*)d_in[10];
  const float* ebn1 = (const float*)d_in[11];
  const float* e2w = (const float*)d_in[12];
  const float* e2b = (const float*)d_in[13];
  const float* ebn2 = (const float*)d_in[14];
  const float* e3w = (const float*)d_in[15];
  const float* e3b = (const float*)d_in[16];
  const float* ebn3 = (const float*)d_in[17];
  const float* f1w = (const float*)d_in[18];
  const float* f1b = (const float*)d_in[19];
  const float* f2w = (const float*)d_in[20];
  const float* f2b = (const float*)d_in[21];
  float* out = (float*)d_out;

  const int B = in_sizes[0] / 60;  // 16384

  transpose_w_kernel<<<(47616 + 255) / 256, 256, 0, stream>>>(gcw, e2w, e3w,
                                                              ebn2, ebn3);
  build_p_kernel<<<(50064 + 255) / 256, 256, 0, stream>>>(
      embt, gcw, e1w, gbn, gcb, ebn1, e1b, ebn2, e2b, ebn3, e3b);
  moe_fused_kernel<<<B, 256, 0, stream>>>(x, embt, gcb, gbn, gf1w, gf1b, gf2w,
                                          gf2b, f1w, f1b, f2w, f2b, out);
}